// Round 2
// baseline (3680.590 us; speedup 1.0000x reference)
//
#include <hip/hip_runtime.h>
#include <cfloat>

#define N_Q     65536
#define D_DIM   256
#define K_CODES 1024

// output float offsets (tuple concatenated flat, all as float32)
#define OUT_QST   0
#define OUT_LOSS  16777216
#define OUT_IDX   16777217
#define OUT_EMBED 16842753
#define OUT_COUNT 17104897
#define OUT_EMAW  17105921

// workspace byte offsets
#define WS_IDX   0u          // 65536*4 int argmin
#define WS_ZZ    262144u     // 65536*4 float ||z||^2
#define WS_PERM  524288u     // 65536*4 int CSR permutation
#define WS_PACK  786432u     // 65536*8 uint64 packed (dist,idx), memset 0xFF
#define WS_EN    1310720u    // 1024*4 float ||e||^2
#define WS_ICNT  1314816u    // 1024*4 int counts, zeroed
#define WS_OFFS  1318912u    // 1024*4 int CSR offsets
#define WS_OFFW  1323008u    // 1024*4 int CSR fill cursor
#define WS_CNTF  1327104u    // 1024*4 float counts
#define WS_CS    1331200u    // 1024*4 float laplace-smoothed counts
#define WS_LOSS  1335296u    // 8 double loss accum, zeroed

// ---------------------------------------------------------------------------
// row-wise sum of squares for a [rows, 256] matrix; one wave per row
__global__ void rownorm2_kernel(const float* __restrict__ x, float* __restrict__ out)
{
    int wave = threadIdx.x >> 6, lane = threadIdx.x & 63;
    int row  = blockIdx.x * 4 + wave;
    const float4 v = *(const float4*)&x[(size_t)row * D_DIM + lane * 4];
    float s = v.x * v.x + v.y * v.y + v.z * v.z + v.w * v.w;
    #pragma unroll
    for (int m = 32; m >= 1; m >>= 1) s += __shfl_down(s, m, 64);
    if (lane == 0) out[row] = s;
}

// ---------------------------------------------------------------------------
// fused distance + argmin, K split across blockIdx.y (2 halves of 512 codes).
// Block: 128 queries x 128-code chunks, D chunked by 32. Thread: 8q x 8c tile.
// Score replicates np op order: fl(fl(zz - fl(2*dot)) + e_norm); result merged
// via atomicMin on packed (dist_bits<<32)|idx  -> exact first-index tie-break
// (dist always positive here: zz ~ 256 >> |2 dot|).
#define MQ   128
#define KC   128
#define DK   32
#define LSTR 36   // +4 pad: LDS read conflicts <= 2-way (free), float2/4 aligned

__launch_bounds__(256, 4)
__global__ void argmin_kernel(const float* __restrict__ z,
                              const float* __restrict__ embed,
                              const float* __restrict__ enorm,
                              const float* __restrict__ zz,
                              unsigned long long* __restrict__ pack)
{
    __shared__ float Zs[MQ * LSTR];
    __shared__ float Es[KC * LSTR];
    const int t  = threadIdx.x;
    const int tx = t & 15, ty = t >> 4;
    const int qbase = blockIdx.x * MQ;
    const int kc0   = blockIdx.y * 4;   // 4 chunks of 128 codes per half

    float aq[8];
    #pragma unroll
    for (int j = 0; j < 8; ++j) aq[j] = zz[qbase + ty + 16 * j];

    float rv[8];
    int   rc[8];
    #pragma unroll
    for (int j = 0; j < 8; ++j) { rv[j] = FLT_MAX; rc[j] = 0x7fffffff; }

    for (int kk = 0; kk < 4; ++kk) {
        const int kc = kc0 + kk;
        float acc[8][8];
        #pragma unroll
        for (int j = 0; j < 8; ++j)
            #pragma unroll
            for (int i = 0; i < 8; ++i) acc[j][i] = 0.f;

        for (int dk = 0; dk < D_DIM / DK; ++dk) {
            __syncthreads();
            #pragma unroll
            for (int r = 0; r < 4; ++r) {
                int lin = r * 256 + t;
                int row = lin >> 3, f4 = lin & 7;
                *(float4*)&Zs[row * LSTR + f4 * 4] =
                    *(const float4*)&z[(size_t)(qbase + row) * D_DIM + dk * DK + f4 * 4];
            }
            #pragma unroll
            for (int r = 0; r < 4; ++r) {
                int lin = r * 256 + t;
                int row = lin >> 3, f4 = lin & 7;
                *(float4*)&Es[row * LSTR + f4 * 4] =
                    *(const float4*)&embed[(size_t)(kc * KC + row) * D_DIM + dk * DK + f4 * 4];
            }
            __syncthreads();
            #pragma unroll
            for (int d2 = 0; d2 < DK / 2; ++d2) {
                float2 zf[8], ef[8];
                #pragma unroll
                for (int j = 0; j < 8; ++j)
                    zf[j] = *(const float2*)&Zs[(ty + 16 * j) * LSTR + d2 * 2];
                #pragma unroll
                for (int i = 0; i < 8; ++i)
                    ef[i] = *(const float2*)&Es[(tx + 16 * i) * LSTR + d2 * 2];
                #pragma unroll
                for (int j = 0; j < 8; ++j)
                    #pragma unroll
                    for (int i = 0; i < 8; ++i) {
                        acc[j][i] += zf[j].x * ef[i].x;
                        acc[j][i] += zf[j].y * ef[i].y;
                    }
            }
        }
        // epilogue for this 128-code chunk
        float en[8];
        #pragma unroll
        for (int i = 0; i < 8; ++i) en[i] = enorm[kc * KC + tx + 16 * i];
        #pragma unroll
        for (int j = 0; j < 8; ++j) {
            float bv = FLT_MAX;
            int   bc = 0x7fffffff;
            #pragma unroll
            for (int i = 0; i < 8; ++i) {
                float b  = 2.0f * acc[j][i];   // exact (x2)
                float t1 = aq[j] - b;          // fp32 round at |zz| scale (matches np)
                float s  = t1 + en[i];         // fp32 round again (matches np)
                int   c  = kc * KC + tx + 16 * i;
                if (s < bv) { bv = s; bc = c; }  // ascending c: first-idx tie
            }
            #pragma unroll
            for (int m = 1; m < 16; m <<= 1) {
                float ov = __shfl_xor(bv, m, 64);
                int   oc = __shfl_xor(bc, m, 64);
                if (ov < bv || (ov == bv && oc < bc)) { bv = ov; bc = oc; }
            }
            if (bv < rv[j] || (bv == rv[j] && bc < rc[j])) { rv[j] = bv; rc[j] = bc; }
        }
    }
    if (tx == 0) {
        #pragma unroll
        for (int j = 0; j < 8; ++j) {
            int n = qbase + ty + 16 * j;
            unsigned long long pk =
                ((unsigned long long)__float_as_uint(rv[j]) << 32) | (unsigned)rc[j];
            atomicMin(&pack[n], pk);
        }
    }
}

// ---------------------------------------------------------------------------
// unpack winner, write idx (int + float), histogram counts
__global__ void unpack_kernel(const unsigned long long* __restrict__ pack,
                              int* __restrict__ idx_i,
                              float* __restrict__ idx_f,
                              int* __restrict__ icnt)
{
    int n = blockIdx.x * 256 + threadIdx.x;
    int k = (int)(pack[n] & 0xffffffffull);
    idx_i[n] = k;
    idx_f[n] = (float)k;
    atomicAdd(&icnt[k], 1);
}

// ---------------------------------------------------------------------------
// exclusive scan of counts (1 block x 1024) -> offsets + fill cursor + float counts
__global__ void scan_kernel(const int* __restrict__ icnt,
                            int* __restrict__ offs,
                            int* __restrict__ offw,
                            float* __restrict__ cntf)
{
    __shared__ int s[1024];
    int t = threadIdx.x;
    int v0 = icnt[t];
    s[t] = v0;
    __syncthreads();
    for (int d = 1; d < 1024; d <<= 1) {
        int v = (t >= d) ? s[t - d] : 0;
        __syncthreads();
        s[t] += v;
        __syncthreads();
    }
    int excl = s[t] - v0;
    offs[t] = excl;
    offw[t] = excl;
    cntf[t] = (float)v0;
}

// ---------------------------------------------------------------------------
// build CSR permutation (order within a code arbitrary; accum uses double)
__global__ void fill_kernel(const int* __restrict__ idx,
                            int* __restrict__ offw,
                            int* __restrict__ perm)
{
    int n = blockIdx.x * 256 + threadIdx.x;
    int k = idx[n];
    int pos = atomicAdd(&offw[k], 1);
    perm[pos] = n;
}

// ---------------------------------------------------------------------------
// gather q = embed[idx], write q_st = z + (q - z), accumulate sum((z-q)^2)
__global__ void qst_loss_kernel(const float* __restrict__ z,
                                const float* __restrict__ embed,
                                const int* __restrict__ idx,
                                float* __restrict__ qst,
                                double* __restrict__ loss)
{
    int tid = blockIdx.x * blockDim.x + threadIdx.x;
    int e0  = tid * 4;
    int n   = e0 >> 8, d = e0 & 255;
    int k   = idx[n];
    const float4 q4 = *(const float4*)&embed[(size_t)k * D_DIM + d];
    const float4 z4 = *(const float4*)&z[e0];
    float4 o;
    o.x = z4.x + (q4.x - z4.x);
    o.y = z4.y + (q4.y - z4.y);
    o.z = z4.z + (q4.z - z4.z);
    o.w = z4.w + (q4.w - z4.w);
    *(float4*)&qst[e0] = o;
    float dx = z4.x - q4.x, dy = z4.y - q4.y, dz = z4.z - q4.z, dw = z4.w - q4.w;
    float s = dx * dx + dy * dy + dz * dz + dw * dw;
    #pragma unroll
    for (int m = 32; m >= 1; m >>= 1) s += __shfl_down(s, m, 64);
    __shared__ float ps[4];
    int wave = threadIdx.x >> 6, lane = threadIdx.x & 63;
    if (lane == 0) ps[wave] = s;
    __syncthreads();
    if (threadIdx.x == 0)
        atomicAdd(loss, (double)((ps[0] + ps[1]) + (ps[2] + ps[3])));
}

// ---------------------------------------------------------------------------
// new_count, n = sum(new_count), cs, vq_loss finalize (single block of 1024)
__global__ void fin_counts_kernel(const float* __restrict__ ema_count,
                                  const float* __restrict__ cntf,
                                  const double* __restrict__ loss,
                                  float* __restrict__ out_count,
                                  float* __restrict__ out_loss,
                                  float* __restrict__ cs)
{
    __shared__ float red[1024];
    int t = threadIdx.x;
    float c = 0.99f * ema_count[t] + 0.01f * cntf[t];
    out_count[t] = c;
    red[t] = c;
    __syncthreads();
    for (int s = 512; s >= 1; s >>= 1) {
        if (t < s) red[t] += red[t + s];
        __syncthreads();
    }
    float n = red[0];
    cs[t] = (c + 1e-5f) / (n + 1024.0f * 1e-5f) * n;
    if (t == 0) {
        float m = (float)(loss[0] / (double)((size_t)N_Q * D_DIM));
        out_loss[0] = m + 0.25f * m;   // codebook + BETA*commit, bitwise equal halves
    }
}

// ---------------------------------------------------------------------------
// per-code: dw[k,d] = sum over members of z (double accum), then EMA + normalize.
// One block per code; thread t handles column d=t; rows staged via LDS.
__global__ void accum_embed_kernel(const float* __restrict__ z,
                                   const int* __restrict__ perm,
                                   const int* __restrict__ icnt,
                                   const int* __restrict__ offs,
                                   const float* __restrict__ cs,
                                   const float* __restrict__ ema_w,
                                   float* __restrict__ out_embed,
                                   float* __restrict__ out_emaw)
{
    __shared__ int rows[256];
    int k = blockIdx.x, t = threadIdx.x;
    int cnt = icnt[k], off = offs[k];
    double acc = 0.0;
    for (int base = 0; base < cnt; base += 256) {
        int m = min(256, cnt - base);
        __syncthreads();
        if (t < m) rows[t] = perm[off + base + t];
        __syncthreads();
        for (int r = 0; r < m; ++r)
            acc += (double)z[(size_t)rows[r] * D_DIM + t];
    }
    float w = 0.99f * ema_w[(size_t)k * D_DIM + t] + 0.01f * (float)acc;
    out_emaw[(size_t)k * D_DIM + t]  = w;
    out_embed[(size_t)k * D_DIM + t] = w / cs[k];
}

// ---------------------------------------------------------------------------
extern "C" void kernel_launch(void* const* d_in, const int* in_sizes, int n_in,
                              void* d_out, int out_size, void* d_ws, size_t ws_size,
                              hipStream_t stream)
{
    const float* z          = (const float*)d_in[0];
    const float* embed      = (const float*)d_in[1];
    const float* ema_count  = (const float*)d_in[2];
    const float* ema_weight = (const float*)d_in[3];
    float* out = (float*)d_out;
    char*  ws  = (char*)d_ws;

    int*    ws_idx  = (int*)(ws + WS_IDX);
    float*  ws_zz   = (float*)(ws + WS_ZZ);
    int*    ws_perm = (int*)(ws + WS_PERM);
    unsigned long long* ws_pack = (unsigned long long*)(ws + WS_PACK);
    float*  ws_en   = (float*)(ws + WS_EN);
    int*    ws_icnt = (int*)(ws + WS_ICNT);
    int*    ws_offs = (int*)(ws + WS_OFFS);
    int*    ws_offw = (int*)(ws + WS_OFFW);
    float*  ws_cntf = (float*)(ws + WS_CNTF);
    float*  ws_cs   = (float*)(ws + WS_CS);
    double* ws_loss = (double*)(ws + WS_LOSS);

    hipMemsetAsync(ws + WS_PACK, 0xFF, (size_t)N_Q * 8, stream);
    hipMemsetAsync(ws + WS_ICNT, 0, 4096, stream);
    hipMemsetAsync(ws + WS_LOSS, 0, 8, stream);

    rownorm2_kernel<<<K_CODES / 4, 256, 0, stream>>>(embed, ws_en);
    rownorm2_kernel<<<N_Q / 4,     256, 0, stream>>>(z, ws_zz);
    argmin_kernel<<<dim3(N_Q / MQ, 2), 256, 0, stream>>>(z, embed, ws_en, ws_zz,
                                                         ws_pack);
    unpack_kernel<<<N_Q / 256, 256, 0, stream>>>(ws_pack, ws_idx,
                                                 out + OUT_IDX, ws_icnt);
    scan_kernel<<<1, 1024, 0, stream>>>(ws_icnt, ws_offs, ws_offw, ws_cntf);
    fill_kernel<<<N_Q / 256, 256, 0, stream>>>(ws_idx, ws_offw, ws_perm);
    qst_loss_kernel<<<(N_Q * (D_DIM / 4)) / 256, 256, 0, stream>>>(
        z, embed, ws_idx, out + OUT_QST, ws_loss);
    fin_counts_kernel<<<1, 1024, 0, stream>>>(ema_count, ws_cntf, ws_loss,
                                              out + OUT_COUNT, out + OUT_LOSS, ws_cs);
    accum_embed_kernel<<<K_CODES, 256, 0, stream>>>(z, ws_perm, ws_icnt, ws_offs,
                                                    ws_cs, ema_weight,
                                                    out + OUT_EMBED, out + OUT_EMAW);
}

// Round 3
// 1801.483 us; speedup vs baseline: 2.0431x; 2.0431x over previous
//
#include <hip/hip_runtime.h>
#include <cfloat>

#define N_Q     65536
#define D_DIM   256
#define K_CODES 1024

// output float offsets (tuple concatenated flat, all as float32)
#define OUT_QST   0
#define OUT_LOSS  16777216
#define OUT_IDX   16777217
#define OUT_EMBED 16842753
#define OUT_COUNT 17104897
#define OUT_EMAW  17105921

// workspace byte offsets
#define WS_IDX   0u          // 65536*4 int argmin
#define WS_ZZ    262144u     // 65536*4 float ||z||^2
#define WS_PERM  524288u     // 65536*4 int CSR permutation
#define WS_PACK  786432u     // 65536*8 uint64 packed (dist,idx), memset 0xFF
#define WS_EN    1310720u    // 1024*4 float ||e||^2
#define WS_ICNT  1314816u    // 1024*4 int counts, zeroed
#define WS_OFFS  1318912u    // 1024*4 int CSR offsets
#define WS_OFFW  1323008u    // 1024*4 int CSR fill cursor
#define WS_CNTF  1327104u    // 1024*4 float counts
#define WS_CS    1331200u    // 1024*4 float laplace-smoothed counts
#define WS_LOSS  1335296u    // 8 double loss accum, zeroed

// ---------------------------------------------------------------------------
// row-wise sum of squares for a [rows, 256] matrix; one wave per row
__global__ void rownorm2_kernel(const float* __restrict__ x, float* __restrict__ out)
{
    int wave = threadIdx.x >> 6, lane = threadIdx.x & 63;
    int row  = blockIdx.x * 4 + wave;
    const float4 v = *(const float4*)&x[(size_t)row * D_DIM + lane * 4];
    float s = v.x * v.x + v.y * v.y + v.z * v.z + v.w * v.w;
    #pragma unroll
    for (int m = 32; m >= 1; m >>= 1) s += __shfl_down(s, m, 64);
    if (lane == 0) out[row] = s;
}

// ---------------------------------------------------------------------------
// fused distance + argmin, K split across blockIdx.y (2 halves of 512 codes).
// Block: 128 queries x 128-code chunks, D chunked by 32. Thread: 8q x 8c tile.
// Inner loop: float4 LDS reads (16 ds_read_b128 feed 256 FMAs per 4-d step).
// Score replicates np op order: fl(fl(zz - 2*dot) + e_norm), dot accumulated
// sequentially in d-order (precision anchor from R1). Winner merged via
// atomicMin on packed (dist_bits<<32)|idx -> exact first-index tie-break
// (dist always positive: zz ~ 256 >> |2 dot|).
#define MQ   128
#define KC   128
#define DK   32
#define LSTR 36   // +4 pad: ef-read 2-way conflict only (free), float4-aligned

__launch_bounds__(256, 2)   // (256,4) in R2 capped VGPR at 64 -> acc spill, 12.6 GB scratch traffic
__global__ void argmin_kernel(const float* __restrict__ z,
                              const float* __restrict__ embed,
                              const float* __restrict__ enorm,
                              const float* __restrict__ zz,
                              unsigned long long* __restrict__ pack)
{
    __shared__ float Zs[MQ * LSTR];
    __shared__ float Es[KC * LSTR];
    const int t  = threadIdx.x;
    const int tx = t & 15, ty = t >> 4;
    const int qbase = blockIdx.x * MQ;
    const int kc0   = blockIdx.y * 4;   // 4 chunks of 128 codes per half

    float aq[8];
    #pragma unroll
    for (int j = 0; j < 8; ++j) aq[j] = zz[qbase + ty + 16 * j];

    float rv[8];
    int   rc[8];
    #pragma unroll
    for (int j = 0; j < 8; ++j) { rv[j] = FLT_MAX; rc[j] = 0x7fffffff; }

    for (int kk = 0; kk < 4; ++kk) {
        const int kc = kc0 + kk;
        float acc[8][8];
        #pragma unroll
        for (int j = 0; j < 8; ++j)
            #pragma unroll
            for (int i = 0; i < 8; ++i) acc[j][i] = 0.f;

        for (int dk = 0; dk < D_DIM / DK; ++dk) {
            __syncthreads();
            #pragma unroll
            for (int r = 0; r < 4; ++r) {
                int lin = r * 256 + t;
                int row = lin >> 3, f4 = lin & 7;
                *(float4*)&Zs[row * LSTR + f4 * 4] =
                    *(const float4*)&z[(size_t)(qbase + row) * D_DIM + dk * DK + f4 * 4];
            }
            #pragma unroll
            for (int r = 0; r < 4; ++r) {
                int lin = r * 256 + t;
                int row = lin >> 3, f4 = lin & 7;
                *(float4*)&Es[row * LSTR + f4 * 4] =
                    *(const float4*)&embed[(size_t)(kc * KC + row) * D_DIM + dk * DK + f4 * 4];
            }
            __syncthreads();
            #pragma unroll
            for (int d4 = 0; d4 < DK / 4; ++d4) {
                float4 zf[8], ef[8];
                #pragma unroll
                for (int j = 0; j < 8; ++j)
                    zf[j] = *(const float4*)&Zs[(ty + 16 * j) * LSTR + d4 * 4];
                #pragma unroll
                for (int i = 0; i < 8; ++i)
                    ef[i] = *(const float4*)&Es[(tx + 16 * i) * LSTR + d4 * 4];
                #pragma unroll
                for (int j = 0; j < 8; ++j)
                    #pragma unroll
                    for (int i = 0; i < 8; ++i) {
                        acc[j][i] += zf[j].x * ef[i].x;   // strict d-order
                        acc[j][i] += zf[j].y * ef[i].y;
                        acc[j][i] += zf[j].z * ef[i].z;
                        acc[j][i] += zf[j].w * ef[i].w;
                    }
            }
        }
        // epilogue for this 128-code chunk
        float en[8];
        #pragma unroll
        for (int i = 0; i < 8; ++i) en[i] = enorm[kc * KC + tx + 16 * i];
        #pragma unroll
        for (int j = 0; j < 8; ++j) {
            float bv = FLT_MAX;
            int   bc = 0x7fffffff;
            #pragma unroll
            for (int i = 0; i < 8; ++i) {
                float b  = 2.0f * acc[j][i];   // exact (x2)
                float t1 = aq[j] - b;          // fp32 round at |zz| scale (matches np)
                float s  = t1 + en[i];         // fp32 round again (matches np)
                int   c  = kc * KC + tx + 16 * i;
                if (s < bv) { bv = s; bc = c; }  // ascending c: first-idx tie
            }
            #pragma unroll
            for (int m = 1; m < 16; m <<= 1) {
                float ov = __shfl_xor(bv, m, 64);
                int   oc = __shfl_xor(bc, m, 64);
                if (ov < bv || (ov == bv && oc < bc)) { bv = ov; bc = oc; }
            }
            if (bv < rv[j] || (bv == rv[j] && bc < rc[j])) { rv[j] = bv; rc[j] = bc; }
        }
    }
    if (tx == 0) {
        #pragma unroll
        for (int j = 0; j < 8; ++j) {
            int n = qbase + ty + 16 * j;
            unsigned long long pk =
                ((unsigned long long)__float_as_uint(rv[j]) << 32) | (unsigned)rc[j];
            atomicMin(&pack[n], pk);
        }
    }
}

// ---------------------------------------------------------------------------
// unpack winner, write idx (int + float), histogram counts
__global__ void unpack_kernel(const unsigned long long* __restrict__ pack,
                              int* __restrict__ idx_i,
                              float* __restrict__ idx_f,
                              int* __restrict__ icnt)
{
    int n = blockIdx.x * 256 + threadIdx.x;
    int k = (int)(pack[n] & 0xffffffffull);
    idx_i[n] = k;
    idx_f[n] = (float)k;
    atomicAdd(&icnt[k], 1);
}

// ---------------------------------------------------------------------------
// exclusive scan of counts (1 block x 1024) -> offsets + fill cursor + float counts
__global__ void scan_kernel(const int* __restrict__ icnt,
                            int* __restrict__ offs,
                            int* __restrict__ offw,
                            float* __restrict__ cntf)
{
    __shared__ int s[1024];
    int t = threadIdx.x;
    int v0 = icnt[t];
    s[t] = v0;
    __syncthreads();
    for (int d = 1; d < 1024; d <<= 1) {
        int v = (t >= d) ? s[t - d] : 0;
        __syncthreads();
        s[t] += v;
        __syncthreads();
    }
    int excl = s[t] - v0;
    offs[t] = excl;
    offw[t] = excl;
    cntf[t] = (float)v0;
}

// ---------------------------------------------------------------------------
// build CSR permutation (order within a code arbitrary; accum uses double)
__global__ void fill_kernel(const int* __restrict__ idx,
                            int* __restrict__ offw,
                            int* __restrict__ perm)
{
    int n = blockIdx.x * 256 + threadIdx.x;
    int k = idx[n];
    int pos = atomicAdd(&offw[k], 1);
    perm[pos] = n;
}

// ---------------------------------------------------------------------------
// gather q = embed[idx], write q_st = z + (q - z), accumulate sum((z-q)^2)
__global__ void qst_loss_kernel(const float* __restrict__ z,
                                const float* __restrict__ embed,
                                const int* __restrict__ idx,
                                float* __restrict__ qst,
                                double* __restrict__ loss)
{
    int tid = blockIdx.x * blockDim.x + threadIdx.x;
    int e0  = tid * 4;
    int n   = e0 >> 8, d = e0 & 255;
    int k   = idx[n];
    const float4 q4 = *(const float4*)&embed[(size_t)k * D_DIM + d];
    const float4 z4 = *(const float4*)&z[e0];
    float4 o;
    o.x = z4.x + (q4.x - z4.x);
    o.y = z4.y + (q4.y - z4.y);
    o.z = z4.z + (q4.z - z4.z);
    o.w = z4.w + (q4.w - z4.w);
    *(float4*)&qst[e0] = o;
    float dx = z4.x - q4.x, dy = z4.y - q4.y, dz = z4.z - q4.z, dw = z4.w - q4.w;
    float s = dx * dx + dy * dy + dz * dz + dw * dw;
    #pragma unroll
    for (int m = 32; m >= 1; m >>= 1) s += __shfl_down(s, m, 64);
    __shared__ float ps[4];
    int wave = threadIdx.x >> 6, lane = threadIdx.x & 63;
    if (lane == 0) ps[wave] = s;
    __syncthreads();
    if (threadIdx.x == 0)
        atomicAdd(loss, (double)((ps[0] + ps[1]) + (ps[2] + ps[3])));
}

// ---------------------------------------------------------------------------
// new_count, n = sum(new_count), cs, vq_loss finalize (single block of 1024)
__global__ void fin_counts_kernel(const float* __restrict__ ema_count,
                                  const float* __restrict__ cntf,
                                  const double* __restrict__ loss,
                                  float* __restrict__ out_count,
                                  float* __restrict__ out_loss,
                                  float* __restrict__ cs)
{
    __shared__ float red[1024];
    int t = threadIdx.x;
    float c = 0.99f * ema_count[t] + 0.01f * cntf[t];
    out_count[t] = c;
    red[t] = c;
    __syncthreads();
    for (int s = 512; s >= 1; s >>= 1) {
        if (t < s) red[t] += red[t + s];
        __syncthreads();
    }
    float n = red[0];
    cs[t] = (c + 1e-5f) / (n + 1024.0f * 1e-5f) * n;
    if (t == 0) {
        float m = (float)(loss[0] / (double)((size_t)N_Q * D_DIM));
        out_loss[0] = m + 0.25f * m;   // codebook + BETA*commit, bitwise equal halves
    }
}

// ---------------------------------------------------------------------------
// per-code: dw[k,d] = sum over members of z (double accum), then EMA + normalize.
// One block per code; thread t handles column d=t; rows staged via LDS.
__global__ void accum_embed_kernel(const float* __restrict__ z,
                                   const int* __restrict__ perm,
                                   const int* __restrict__ icnt,
                                   const int* __restrict__ offs,
                                   const float* __restrict__ cs,
                                   const float* __restrict__ ema_w,
                                   float* __restrict__ out_embed,
                                   float* __restrict__ out_emaw)
{
    __shared__ int rows[256];
    int k = blockIdx.x, t = threadIdx.x;
    int cnt = icnt[k], off = offs[k];
    double acc = 0.0;
    for (int base = 0; base < cnt; base += 256) {
        int m = min(256, cnt - base);
        __syncthreads();
        if (t < m) rows[t] = perm[off + base + t];
        __syncthreads();
        for (int r = 0; r < m; ++r)
            acc += (double)z[(size_t)rows[r] * D_DIM + t];
    }
    float w = 0.99f * ema_w[(size_t)k * D_DIM + t] + 0.01f * (float)acc;
    out_emaw[(size_t)k * D_DIM + t]  = w;
    out_embed[(size_t)k * D_DIM + t] = w / cs[k];
}

// ---------------------------------------------------------------------------
extern "C" void kernel_launch(void* const* d_in, const int* in_sizes, int n_in,
                              void* d_out, int out_size, void* d_ws, size_t ws_size,
                              hipStream_t stream)
{
    const float* z          = (const float*)d_in[0];
    const float* embed      = (const float*)d_in[1];
    const float* ema_count  = (const float*)d_in[2];
    const float* ema_weight = (const float*)d_in[3];
    float* out = (float*)d_out;
    char*  ws  = (char*)d_ws;

    int*    ws_idx  = (int*)(ws + WS_IDX);
    float*  ws_zz   = (float*)(ws + WS_ZZ);
    int*    ws_perm = (int*)(ws + WS_PERM);
    unsigned long long* ws_pack = (unsigned long long*)(ws + WS_PACK);
    float*  ws_en   = (float*)(ws + WS_EN);
    int*    ws_icnt = (int*)(ws + WS_ICNT);
    int*    ws_offs = (int*)(ws + WS_OFFS);
    int*    ws_offw = (int*)(ws + WS_OFFW);
    float*  ws_cntf = (float*)(ws + WS_CNTF);
    float*  ws_cs   = (float*)(ws + WS_CS);
    double* ws_loss = (double*)(ws + WS_LOSS);

    hipMemsetAsync(ws + WS_PACK, 0xFF, (size_t)N_Q * 8, stream);
    hipMemsetAsync(ws + WS_ICNT, 0, 4096, stream);
    hipMemsetAsync(ws + WS_LOSS, 0, 8, stream);

    rownorm2_kernel<<<K_CODES / 4, 256, 0, stream>>>(embed, ws_en);
    rownorm2_kernel<<<N_Q / 4,     256, 0, stream>>>(z, ws_zz);
    argmin_kernel<<<dim3(N_Q / MQ, 2), 256, 0, stream>>>(z, embed, ws_en, ws_zz,
                                                         ws_pack);
    unpack_kernel<<<N_Q / 256, 256, 0, stream>>>(ws_pack, ws_idx,
                                                 out + OUT_IDX, ws_icnt);
    scan_kernel<<<1, 1024, 0, stream>>>(ws_icnt, ws_offs, ws_offw, ws_cntf);
    fill_kernel<<<N_Q / 256, 256, 0, stream>>>(ws_idx, ws_offw, ws_perm);
    qst_loss_kernel<<<(N_Q * (D_DIM / 4)) / 256, 256, 0, stream>>>(
        z, embed, ws_idx, out + OUT_QST, ws_loss);
    fin_counts_kernel<<<1, 1024, 0, stream>>>(ema_count, ws_cntf, ws_loss,
                                              out + OUT_COUNT, out + OUT_LOSS, ws_cs);
    accum_embed_kernel<<<K_CODES, 256, 0, stream>>>(z, ws_perm, ws_icnt, ws_offs,
                                                    ws_cs, ema_weight,
                                                    out + OUT_EMBED, out + OUT_EMAW);
}

// Round 4
// 911.242 us; speedup vs baseline: 4.0391x; 1.9770x over previous
//
#include <hip/hip_runtime.h>
#include <cfloat>

#define N_Q     65536
#define D_DIM   256
#define K_CODES 1024

// output float offsets (tuple concatenated flat, all as float32)
#define OUT_QST   0
#define OUT_LOSS  16777216
#define OUT_IDX   16777217
#define OUT_EMBED 16842753
#define OUT_COUNT 17104897
#define OUT_EMAW  17105921

// workspace byte offsets
#define WS_IDX   0u          // 65536*4 int argmin
#define WS_ZZ    262144u     // 65536*4 float ||z||^2
#define WS_PERM  524288u     // 65536*4 int CSR permutation
#define WS_PACK  786432u     // 65536*8 uint64 packed (dist,idx), memset 0xFF
#define WS_EN    1310720u    // 1024*4 float ||e||^2
#define WS_ICNT  1314816u    // 1024*4 int counts, zeroed
#define WS_OFFS  1318912u    // 1024*4 int CSR offsets
#define WS_OFFW  1323008u    // 1024*4 int CSR fill cursor
#define WS_CNTF  1327104u    // 1024*4 float counts
#define WS_CS    1331200u    // 1024*4 float laplace-smoothed counts
#define WS_LOSS  1335296u    // 8 double loss accum, zeroed

// ---------------------------------------------------------------------------
// row-wise sum of squares for a [rows, 256] matrix; one wave per row
__global__ void rownorm2_kernel(const float* __restrict__ x, float* __restrict__ out)
{
    int wave = threadIdx.x >> 6, lane = threadIdx.x & 63;
    int row  = blockIdx.x * 4 + wave;
    const float4 v = *(const float4*)&x[(size_t)row * D_DIM + lane * 4];
    float s = v.x * v.x + v.y * v.y + v.z * v.z + v.w * v.w;
    #pragma unroll
    for (int m = 32; m >= 1; m >>= 1) s += __shfl_down(s, m, 64);
    if (lane == 0) out[row] = s;
}

// ---------------------------------------------------------------------------
// fused distance + argmin, K split across blockIdx.y (2 halves of 512 codes).
// Block: 128 queries x 64-code chunks, D chunked by 32. Thread: 8q x 4c tile
// (32 acc regs; 8q x 8c in R3 spilled at the 128-VGPR practical budget ->
//  2.7 GB scratch writes). Inner loop: 12 ds_read_b128 feed 128 FMAs per
// 4-d step. Score replicates np op order: fl(fl(zz - 2*dot) + e_norm), dot
// accumulated in strict d-order. Winner merged via atomicMin on packed
// (dist_bits<<32)|idx -> exact first-index tie-break (dist > 0 always).
#define MQ   128
#define KC   64
#define DK   32
#define LSTR 36   // +4 pad: reads broadcast or 2-way only (free), float4-aligned

__launch_bounds__(256, 2)
__global__ void argmin_kernel(const float* __restrict__ z,
                              const float* __restrict__ embed,
                              const float* __restrict__ enorm,
                              const float* __restrict__ zz,
                              unsigned long long* __restrict__ pack)
{
    __shared__ float Zs[MQ * LSTR];   // 18432 B
    __shared__ float Es[KC * LSTR];   //  9216 B
    const int t  = threadIdx.x;
    const int tx = t & 15, ty = t >> 4;
    const int qbase = blockIdx.x * MQ;
    const int kc0   = blockIdx.y * 8;   // 8 chunks of 64 codes per half

    float aq[8];
    #pragma unroll
    for (int j = 0; j < 8; ++j) aq[j] = zz[qbase + ty + 16 * j];

    float rv[8];
    int   rc[8];
    #pragma unroll
    for (int j = 0; j < 8; ++j) { rv[j] = FLT_MAX; rc[j] = 0x7fffffff; }

    for (int kk = 0; kk < 8; ++kk) {
        const int kc = kc0 + kk;
        float acc[8][4];
        #pragma unroll
        for (int j = 0; j < 8; ++j)
            #pragma unroll
            for (int i = 0; i < 4; ++i) acc[j][i] = 0.f;

        for (int dk = 0; dk < D_DIM / DK; ++dk) {
            __syncthreads();
            #pragma unroll
            for (int r = 0; r < 4; ++r) {            // Z tile: 128 rows x 32 f
                int lin = r * 256 + t;
                int row = lin >> 3, f4 = lin & 7;
                *(float4*)&Zs[row * LSTR + f4 * 4] =
                    *(const float4*)&z[(size_t)(qbase + row) * D_DIM + dk * DK + f4 * 4];
            }
            #pragma unroll
            for (int r = 0; r < 2; ++r) {            // E tile: 64 rows x 32 f
                int lin = r * 256 + t;
                int row = lin >> 3, f4 = lin & 7;
                *(float4*)&Es[row * LSTR + f4 * 4] =
                    *(const float4*)&embed[(size_t)(kc * KC + row) * D_DIM + dk * DK + f4 * 4];
            }
            __syncthreads();
            #pragma unroll
            for (int d4 = 0; d4 < DK / 4; ++d4) {
                float4 zf[8], ef[4];
                #pragma unroll
                for (int j = 0; j < 8; ++j)
                    zf[j] = *(const float4*)&Zs[(ty + 16 * j) * LSTR + d4 * 4];
                #pragma unroll
                for (int i = 0; i < 4; ++i)
                    ef[i] = *(const float4*)&Es[(tx + 16 * i) * LSTR + d4 * 4];
                #pragma unroll
                for (int j = 0; j < 8; ++j)
                    #pragma unroll
                    for (int i = 0; i < 4; ++i) {
                        acc[j][i] += zf[j].x * ef[i].x;   // strict d-order
                        acc[j][i] += zf[j].y * ef[i].y;
                        acc[j][i] += zf[j].z * ef[i].z;
                        acc[j][i] += zf[j].w * ef[i].w;
                    }
            }
        }
        // epilogue for this 64-code chunk
        float en[4];
        #pragma unroll
        for (int i = 0; i < 4; ++i) en[i] = enorm[kc * KC + tx + 16 * i];
        #pragma unroll
        for (int j = 0; j < 8; ++j) {
            float bv = FLT_MAX;
            int   bc = 0x7fffffff;
            #pragma unroll
            for (int i = 0; i < 4; ++i) {
                float b  = 2.0f * acc[j][i];   // exact (x2)
                float t1 = aq[j] - b;          // fp32 round at |zz| scale (matches np)
                float s  = t1 + en[i];         // fp32 round again (matches np)
                int   c  = kc * KC + tx + 16 * i;
                if (s < bv) { bv = s; bc = c; }  // ascending c: first-idx tie
            }
            #pragma unroll
            for (int m = 1; m < 16; m <<= 1) {
                float ov = __shfl_xor(bv, m, 64);
                int   oc = __shfl_xor(bc, m, 64);
                if (ov < bv || (ov == bv && oc < bc)) { bv = ov; bc = oc; }
            }
            if (bv < rv[j] || (bv == rv[j] && bc < rc[j])) { rv[j] = bv; rc[j] = bc; }
        }
    }
    if (tx == 0) {
        #pragma unroll
        for (int j = 0; j < 8; ++j) {
            int n = qbase + ty + 16 * j;
            unsigned long long pk =
                ((unsigned long long)__float_as_uint(rv[j]) << 32) | (unsigned)rc[j];
            atomicMin(&pack[n], pk);
        }
    }
}

// ---------------------------------------------------------------------------
// unpack winner, write idx (int + float), histogram counts
__global__ void unpack_kernel(const unsigned long long* __restrict__ pack,
                              int* __restrict__ idx_i,
                              float* __restrict__ idx_f,
                              int* __restrict__ icnt)
{
    int n = blockIdx.x * 256 + threadIdx.x;
    int k = (int)(pack[n] & 0xffffffffull);
    idx_i[n] = k;
    idx_f[n] = (float)k;
    atomicAdd(&icnt[k], 1);
}

// ---------------------------------------------------------------------------
// exclusive scan of counts (1 block x 1024) -> offsets + fill cursor + float counts
__global__ void scan_kernel(const int* __restrict__ icnt,
                            int* __restrict__ offs,
                            int* __restrict__ offw,
                            float* __restrict__ cntf)
{
    __shared__ int s[1024];
    int t = threadIdx.x;
    int v0 = icnt[t];
    s[t] = v0;
    __syncthreads();
    for (int d = 1; d < 1024; d <<= 1) {
        int v = (t >= d) ? s[t - d] : 0;
        __syncthreads();
        s[t] += v;
        __syncthreads();
    }
    int excl = s[t] - v0;
    offs[t] = excl;
    offw[t] = excl;
    cntf[t] = (float)v0;
}

// ---------------------------------------------------------------------------
// build CSR permutation (order within a code arbitrary; accum uses double)
__global__ void fill_kernel(const int* __restrict__ idx,
                            int* __restrict__ offw,
                            int* __restrict__ perm)
{
    int n = blockIdx.x * 256 + threadIdx.x;
    int k = idx[n];
    int pos = atomicAdd(&offw[k], 1);
    perm[pos] = n;
}

// ---------------------------------------------------------------------------
// gather q = embed[idx], write q_st = z + (q - z), accumulate sum((z-q)^2)
__global__ void qst_loss_kernel(const float* __restrict__ z,
                                const float* __restrict__ embed,
                                const int* __restrict__ idx,
                                float* __restrict__ qst,
                                double* __restrict__ loss)
{
    int tid = blockIdx.x * blockDim.x + threadIdx.x;
    int e0  = tid * 4;
    int n   = e0 >> 8, d = e0 & 255;
    int k   = idx[n];
    const float4 q4 = *(const float4*)&embed[(size_t)k * D_DIM + d];
    const float4 z4 = *(const float4*)&z[e0];
    float4 o;
    o.x = z4.x + (q4.x - z4.x);
    o.y = z4.y + (q4.y - z4.y);
    o.z = z4.z + (q4.z - z4.z);
    o.w = z4.w + (q4.w - z4.w);
    *(float4*)&qst[e0] = o;
    float dx = z4.x - q4.x, dy = z4.y - q4.y, dz = z4.z - q4.z, dw = z4.w - q4.w;
    float s = dx * dx + dy * dy + dz * dz + dw * dw;
    #pragma unroll
    for (int m = 32; m >= 1; m >>= 1) s += __shfl_down(s, m, 64);
    __shared__ float ps[4];
    int wave = threadIdx.x >> 6, lane = threadIdx.x & 63;
    if (lane == 0) ps[wave] = s;
    __syncthreads();
    if (threadIdx.x == 0)
        atomicAdd(loss, (double)((ps[0] + ps[1]) + (ps[2] + ps[3])));
}

// ---------------------------------------------------------------------------
// new_count, n = sum(new_count), cs, vq_loss finalize (single block of 1024)
__global__ void fin_counts_kernel(const float* __restrict__ ema_count,
                                  const float* __restrict__ cntf,
                                  const double* __restrict__ loss,
                                  float* __restrict__ out_count,
                                  float* __restrict__ out_loss,
                                  float* __restrict__ cs)
{
    __shared__ float red[1024];
    int t = threadIdx.x;
    float c = 0.99f * ema_count[t] + 0.01f * cntf[t];
    out_count[t] = c;
    red[t] = c;
    __syncthreads();
    for (int s = 512; s >= 1; s >>= 1) {
        if (t < s) red[t] += red[t + s];
        __syncthreads();
    }
    float n = red[0];
    cs[t] = (c + 1e-5f) / (n + 1024.0f * 1e-5f) * n;
    if (t == 0) {
        float m = (float)(loss[0] / (double)((size_t)N_Q * D_DIM));
        out_loss[0] = m + 0.25f * m;   // codebook + BETA*commit, bitwise equal halves
    }
}

// ---------------------------------------------------------------------------
// per-code: dw[k,d] = sum over members of z (double accum), then EMA + normalize.
// One block per code; thread t handles column d=t; rows staged via LDS.
__global__ void accum_embed_kernel(const float* __restrict__ z,
                                   const int* __restrict__ perm,
                                   const int* __restrict__ icnt,
                                   const int* __restrict__ offs,
                                   const float* __restrict__ cs,
                                   const float* __restrict__ ema_w,
                                   float* __restrict__ out_embed,
                                   float* __restrict__ out_emaw)
{
    __shared__ int rows[256];
    int k = blockIdx.x, t = threadIdx.x;
    int cnt = icnt[k], off = offs[k];
    double acc = 0.0;
    for (int base = 0; base < cnt; base += 256) {
        int m = min(256, cnt - base);
        __syncthreads();
        if (t < m) rows[t] = perm[off + base + t];
        __syncthreads();
        for (int r = 0; r < m; ++r)
            acc += (double)z[(size_t)rows[r] * D_DIM + t];
    }
    float w = 0.99f * ema_w[(size_t)k * D_DIM + t] + 0.01f * (float)acc;
    out_emaw[(size_t)k * D_DIM + t]  = w;
    out_embed[(size_t)k * D_DIM + t] = w / cs[k];
}

// ---------------------------------------------------------------------------
extern "C" void kernel_launch(void* const* d_in, const int* in_sizes, int n_in,
                              void* d_out, int out_size, void* d_ws, size_t ws_size,
                              hipStream_t stream)
{
    const float* z          = (const float*)d_in[0];
    const float* embed      = (const float*)d_in[1];
    const float* ema_count  = (const float*)d_in[2];
    const float* ema_weight = (const float*)d_in[3];
    float* out = (float*)d_out;
    char*  ws  = (char*)d_ws;

    int*    ws_idx  = (int*)(ws + WS_IDX);
    float*  ws_zz   = (float*)(ws + WS_ZZ);
    int*    ws_perm = (int*)(ws + WS_PERM);
    unsigned long long* ws_pack = (unsigned long long*)(ws + WS_PACK);
    float*  ws_en   = (float*)(ws + WS_EN);
    int*    ws_icnt = (int*)(ws + WS_ICNT);
    int*    ws_offs = (int*)(ws + WS_OFFS);
    int*    ws_offw = (int*)(ws + WS_OFFW);
    float*  ws_cntf = (float*)(ws + WS_CNTF);
    float*  ws_cs   = (float*)(ws + WS_CS);
    double* ws_loss = (double*)(ws + WS_LOSS);

    hipMemsetAsync(ws + WS_PACK, 0xFF, (size_t)N_Q * 8, stream);
    hipMemsetAsync(ws + WS_ICNT, 0, 4096, stream);
    hipMemsetAsync(ws + WS_LOSS, 0, 8, stream);

    rownorm2_kernel<<<K_CODES / 4, 256, 0, stream>>>(embed, ws_en);
    rownorm2_kernel<<<N_Q / 4,     256, 0, stream>>>(z, ws_zz);
    argmin_kernel<<<dim3(N_Q / MQ, 2), 256, 0, stream>>>(z, embed, ws_en, ws_zz,
                                                         ws_pack);
    unpack_kernel<<<N_Q / 256, 256, 0, stream>>>(ws_pack, ws_idx,
                                                 out + OUT_IDX, ws_icnt);
    scan_kernel<<<1, 1024, 0, stream>>>(ws_icnt, ws_offs, ws_offw, ws_cntf);
    fill_kernel<<<N_Q / 256, 256, 0, stream>>>(ws_idx, ws_offw, ws_perm);
    qst_loss_kernel<<<(N_Q * (D_DIM / 4)) / 256, 256, 0, stream>>>(
        z, embed, ws_idx, out + OUT_QST, ws_loss);
    fin_counts_kernel<<<1, 1024, 0, stream>>>(ema_count, ws_cntf, ws_loss,
                                              out + OUT_COUNT, out + OUT_LOSS, ws_cs);
    accum_embed_kernel<<<K_CODES, 256, 0, stream>>>(z, ws_perm, ws_icnt, ws_offs,
                                                    ws_cs, ema_weight,
                                                    out + OUT_EMBED, out + OUT_EMAW);
}

// Round 5
// 481.172 us; speedup vs baseline: 7.6492x; 1.8938x over previous
//
#include <hip/hip_runtime.h>
#include <cfloat>

#define N_Q     65536
#define D_DIM   256
#define K_CODES 1024
#define DELTA   0.004f
#define SW_CAP  1536

// output float offsets (tuple concatenated flat, all as float32)
#define OUT_QST   0
#define OUT_LOSS  16777216
#define OUT_IDX   16777217
#define OUT_EMBED 16842753
#define OUT_COUNT 17104897
#define OUT_EMAW  17105921

// workspace byte offsets
#define WS_IDX    0u         // 65536*4 int argmin
#define WS_ZZ     262144u    // 65536*4 float ||z||^2
#define WS_PERM   524288u    // 65536*4 int CSR permutation
#define WS_PACK   786432u    // 65536*8 uint64 packed (dist,idx), memset 0xFF
#define WS_EN     1310720u   // 1024*4 float ||e||^2
#define WS_ICNT   1314816u   // 1024*4 int counts, zeroed
#define WS_OFFS   1318912u   // 1024*4 int CSR offsets
#define WS_OFFW   1323008u   // 1024*4 int CSR fill cursor
#define WS_CNTF   1327104u   // 1024*4 float counts
#define WS_CS     1331200u   // 1024*4 float laplace-smoothed counts
#define WS_MINKEY 1335296u   // 65536*4 uint per-query s1 min key, memset 0xFF
#define WS_THR    1597440u   // 65536*4 float rescore threshold
#define WS_LOSSB  1859584u   // 1024*8 double loss buckets, zeroed

typedef short          bf16x8 __attribute__((ext_vector_type(8)));
typedef unsigned short u16x8  __attribute__((ext_vector_type(8)));
typedef float          f32x4  __attribute__((ext_vector_type(4)));

__device__ inline unsigned short f2bf(float x) {   // RNE fp32 -> bf16
    unsigned u = __float_as_uint(x);
    u += 0x7FFFu + ((u >> 16) & 1u);
    return (unsigned short)(u >> 16);
}
__device__ inline u16x8 pack8(float4 a, float4 b) {
    u16x8 p;
    p[0]=f2bf(a.x); p[1]=f2bf(a.y); p[2]=f2bf(a.z); p[3]=f2bf(a.w);
    p[4]=f2bf(b.x); p[5]=f2bf(b.y); p[6]=f2bf(b.z); p[7]=f2bf(b.w);
    return p;
}
__device__ inline unsigned fkey(float s) {   // order-preserving uint key, any sign
    unsigned b = __float_as_uint(s);
    return b ^ ((b & 0x80000000u) ? 0xFFFFFFFFu : 0x80000000u);
}
__device__ inline float unfkey(unsigned k) {
    return __uint_as_float(k ^ ((k & 0x80000000u) ? 0x80000000u : 0xFFFFFFFFu));
}

// ---------------------------------------------------------------------------
// row-wise sum of squares for a [rows, 256] matrix; one wave per row
__global__ void rownorm2_kernel(const float* __restrict__ x, float* __restrict__ out)
{
    int wave = threadIdx.x >> 6, lane = threadIdx.x & 63;
    int row  = blockIdx.x * 4 + wave;
    const float4 v = *(const float4*)&x[(size_t)row * D_DIM + lane * 4];
    float s = v.x * v.x + v.y * v.y + v.z * v.z + v.w * v.w;
    #pragma unroll
    for (int m = 32; m >= 1; m >>= 1) s += __shfl_down(s, m, 64);
    if (lane == 0) out[row] = s;
}

// ---------------------------------------------------------------------------
// MFMA sweep. Block: 128 queries x all 1024 codes (16 chunks of 64), bf16
// 16x16x32 mfma, fp32 accumulate. s1 = ||e||^2 - 2*dot (zz omitted: constant
// per query). Sweep1 (FILTER=false): per-query global min via packed-uint
// atomicMin. Sweep2 (FILTER=true): candidates with s1 <= min+DELTA pushed to
// an LDS list, then exact fp32 rescore (ref op order fl(fl(zz-2dot)+en),
// first-index ties via packed u64 atomicMin). DELTA = 4e-3 ~ 20 sigma of the
// bf16 input-rounding error (RMS ~3.6e-5 on dot) + the ref's ~2-grid-step
// fp32 quantization reorder -> miss probability negligible; ~1.5 cand/query.
// Layouts (verified, guide §3): A[m=lane&15][k=quad*8+j]; C/D col=lane&15,
// row=quad*4+reg. B loaded from E rows (B^T convention, m91).
template <bool FILTER>
__launch_bounds__(256, 2)
__global__ void sweep_kernel(const float* __restrict__ z,
                             const float* __restrict__ embed,
                             const float* __restrict__ enorm,
                             const float* __restrict__ zz,
                             unsigned* __restrict__ minkey,
                             const float* __restrict__ thr,
                             unsigned long long* __restrict__ pack)
{
    __shared__ unsigned short Zs[128 * 264];   // 67584 B, full-D bf16 z tile
    __shared__ unsigned short Es[64 * 40];     //  5120 B, per-dstep bf16 e tile
    __shared__ unsigned list[SW_CAP];          //  6144 B, sweep2 candidates
    __shared__ int lcnt;

    const int t = threadIdx.x;
    const int w = t >> 6, lane = t & 63;
    const int col = lane & 15, quad = lane >> 4;
    const int qbase = blockIdx.x * 128;

    if (t == 0) lcnt = 0;

    // stage z block -> bf16 LDS once (row stride 264 shorts: 16B-aligned rows,
    // 2-way-max bank aliasing on frag reads)
    {
        int row = t & 127, half = t >> 7;
        const float* src = &z[(size_t)(qbase + row) * D_DIM + half * 128];
        unsigned short* dst = &Zs[row * 264 + half * 128];
        #pragma unroll
        for (int i = 0; i < 16; ++i) {
            float4 a = *(const float4*)&src[i * 8];
            float4 b = *(const float4*)&src[i * 8 + 4];
            *(u16x8*)&dst[i * 8] = pack8(a, b);
        }
    }

    float rstate[2][4];   // sweep1: running min; sweep2: threshold
    #pragma unroll
    for (int rt = 0; rt < 2; ++rt)
        #pragma unroll
        for (int rg = 0; rg < 4; ++rg)
            rstate[rt][rg] = FILTER ? thr[qbase + w*32 + rt*16 + quad*4 + rg]
                                    : FLT_MAX;

    for (int kc = 0; kc < 16; ++kc) {
        f32x4 acc[2][4];
        #pragma unroll
        for (int rt = 0; rt < 2; ++rt)
            #pragma unroll
            for (int ct = 0; ct < 4; ++ct)
                acc[rt][ct] = (f32x4){0.f, 0.f, 0.f, 0.f};

        for (int ds = 0; ds < 8; ++ds) {
            __syncthreads();
            {   // stage E chunk: 64 codes x 32 d
                int r = t >> 2, q4 = t & 3;
                const float* src = &embed[(size_t)(kc*64 + r)*D_DIM + ds*32 + q4*8];
                float4 a = *(const float4*)&src[0];
                float4 b = *(const float4*)&src[4];
                *(u16x8*)&Es[r * 40 + q4 * 8] = pack8(a, b);
            }
            __syncthreads();
            bf16x8 A0 = *(bf16x8*)&Zs[(w*32 +      col) * 264 + ds*32 + quad*8];
            bf16x8 A1 = *(bf16x8*)&Zs[(w*32 + 16 + col) * 264 + ds*32 + quad*8];
            #pragma unroll
            for (int ct = 0; ct < 4; ++ct) {
                bf16x8 B = *(bf16x8*)&Es[(ct*16 + col) * 40 + quad*8];
                acc[0][ct] = __builtin_amdgcn_mfma_f32_16x16x32_bf16(A0, B, acc[0][ct], 0, 0, 0);
                acc[1][ct] = __builtin_amdgcn_mfma_f32_16x16x32_bf16(A1, B, acc[1][ct], 0, 0, 0);
            }
        }

        // epilogue for this 64-code chunk
        #pragma unroll
        for (int ct = 0; ct < 4; ++ct) {
            int k = kc*64 + ct*16 + col;
            float en = enorm[k];
            #pragma unroll
            for (int rt = 0; rt < 2; ++rt)
                #pragma unroll
                for (int rg = 0; rg < 4; ++rg) {
                    float s1 = en - 2.0f * acc[rt][ct][rg];
                    if (FILTER) {
                        if (s1 <= rstate[rt][rg]) {
                            int qloc = w*32 + rt*16 + quad*4 + rg;
                            int pos = atomicAdd(&lcnt, 1);
                            if (pos < SW_CAP) {
                                list[pos] = ((unsigned)qloc << 10) | (unsigned)k;
                            } else {
                                // overflow fallback: exact rescore inline (rare)
                                int qg = qbase + qloc;
                                double dd = 0.0;
                                for (int d = 0; d < D_DIM; d += 4) {
                                    float4 a = *(const float4*)&z[(size_t)qg*D_DIM + d];
                                    float4 b = *(const float4*)&embed[(size_t)k*D_DIM + d];
                                    dd += (double)a.x*b.x + (double)a.y*b.y
                                        + (double)a.z*b.z + (double)a.w*b.w;
                                }
                                float s = (zz[qg] - 2.0f*(float)dd) + en;
                                unsigned long long pk =
                                    ((unsigned long long)__float_as_uint(s) << 32) | (unsigned)k;
                                atomicMin(&pack[qg], pk);
                            }
                        }
                    } else {
                        rstate[rt][rg] = fminf(rstate[rt][rg], s1);
                    }
                }
        }
    }

    if (!FILTER) {
        // per-query min: reduce across the 16 col-lanes, then global atomicMin
        #pragma unroll
        for (int rt = 0; rt < 2; ++rt)
            #pragma unroll
            for (int rg = 0; rg < 4; ++rg) {
                float v = rstate[rt][rg];
                #pragma unroll
                for (int m = 1; m < 16; m <<= 1)
                    v = fminf(v, __shfl_xor(v, m, 64));
                if (col == 0)
                    atomicMin(&minkey[qbase + w*32 + rt*16 + quad*4 + rg], fkey(v));
            }
    } else {
        // exact rescore of candidates: one wave per entry, lane covers 4 d
        __syncthreads();
        int cnt = min(lcnt, SW_CAP);
        for (int e = w; e < cnt; e += 4) {
            unsigned ent = list[e];
            int qloc = (int)(ent >> 10), k = (int)(ent & 1023u);
            int qg = qbase + qloc;
            float4 a = *(const float4*)&z[(size_t)qg*D_DIM + lane*4];
            float4 b = *(const float4*)&embed[(size_t)k*D_DIM + lane*4];
            double dd = (double)a.x*b.x + (double)a.y*b.y
                      + (double)a.z*b.z + (double)a.w*b.w;
            #pragma unroll
            for (int m = 32; m >= 1; m >>= 1)
                dd += __shfl_xor(dd, m, 64);
            if (lane == 0) {
                float s = (zz[qg] - 2.0f*(float)dd) + enorm[k];  // ref op order
                unsigned long long pk =
                    ((unsigned long long)__float_as_uint(s) << 32) | (unsigned)k;
                atomicMin(&pack[qg], pk);
            }
        }
    }
}

// ---------------------------------------------------------------------------
__global__ void thr_kernel(const unsigned* __restrict__ mk, float* __restrict__ thr)
{
    int q = blockIdx.x * 256 + threadIdx.x;
    thr[q] = unfkey(mk[q]) + DELTA;
}

// ---------------------------------------------------------------------------
// unpack winner, write idx (int + float), histogram counts
__global__ void unpack_kernel(const unsigned long long* __restrict__ pack,
                              int* __restrict__ idx_i,
                              float* __restrict__ idx_f,
                              int* __restrict__ icnt)
{
    int n = blockIdx.x * 256 + threadIdx.x;
    int k = (int)(pack[n] & 0xffffffffull);
    idx_i[n] = k;
    idx_f[n] = (float)k;
    atomicAdd(&icnt[k], 1);
}

// ---------------------------------------------------------------------------
// exclusive scan of counts (1 block x 1024) -> offsets + fill cursor + float counts
__global__ void scan_kernel(const int* __restrict__ icnt,
                            int* __restrict__ offs,
                            int* __restrict__ offw,
                            float* __restrict__ cntf)
{
    __shared__ int s[1024];
    int t = threadIdx.x;
    int v0 = icnt[t];
    s[t] = v0;
    __syncthreads();
    for (int d = 1; d < 1024; d <<= 1) {
        int v = (t >= d) ? s[t - d] : 0;
        __syncthreads();
        s[t] += v;
        __syncthreads();
    }
    int excl = s[t] - v0;
    offs[t] = excl;
    offw[t] = excl;
    cntf[t] = (float)v0;
}

// ---------------------------------------------------------------------------
// build CSR permutation (order within a code arbitrary; accum uses double)
__global__ void fill_kernel(const int* __restrict__ idx,
                            int* __restrict__ offw,
                            int* __restrict__ perm)
{
    int n = blockIdx.x * 256 + threadIdx.x;
    int k = idx[n];
    int pos = atomicAdd(&offw[k], 1);
    perm[pos] = n;
}

// ---------------------------------------------------------------------------
// gather q = embed[idx], write q_st = z + (q - z), accumulate sum((z-q)^2)
// into 1024 double buckets (single-address fp64 atomic serialized in R1-R4)
__global__ void qst_loss_kernel(const float* __restrict__ z,
                                const float* __restrict__ embed,
                                const int* __restrict__ idx,
                                float* __restrict__ qst,
                                double* __restrict__ lossb)
{
    int tid = blockIdx.x * blockDim.x + threadIdx.x;
    int e0  = tid * 4;
    int n   = e0 >> 8, d = e0 & 255;
    int k   = idx[n];
    const float4 q4 = *(const float4*)&embed[(size_t)k * D_DIM + d];
    const float4 z4 = *(const float4*)&z[e0];
    float4 o;
    o.x = z4.x + (q4.x - z4.x);
    o.y = z4.y + (q4.y - z4.y);
    o.z = z4.z + (q4.z - z4.z);
    o.w = z4.w + (q4.w - z4.w);
    *(float4*)&qst[e0] = o;
    float dx = z4.x - q4.x, dy = z4.y - q4.y, dz = z4.z - q4.z, dw = z4.w - q4.w;
    float s = dx * dx + dy * dy + dz * dz + dw * dw;
    #pragma unroll
    for (int m = 32; m >= 1; m >>= 1) s += __shfl_down(s, m, 64);
    __shared__ float ps[4];
    int wave = threadIdx.x >> 6, lane = threadIdx.x & 63;
    if (lane == 0) ps[wave] = s;
    __syncthreads();
    if (threadIdx.x == 0)
        atomicAdd(&lossb[blockIdx.x & 1023],
                  (double)((ps[0] + ps[1]) + (ps[2] + ps[3])));
}

// ---------------------------------------------------------------------------
// new_count, n = sum(new_count), cs, vq_loss finalize (single block of 1024)
__global__ void fin_counts_kernel(const float* __restrict__ ema_count,
                                  const float* __restrict__ cntf,
                                  const double* __restrict__ lossb,
                                  float* __restrict__ out_count,
                                  float* __restrict__ out_loss,
                                  float* __restrict__ cs)
{
    __shared__ float  red[1024];
    __shared__ double dred[1024];
    int t = threadIdx.x;
    float c = 0.99f * ema_count[t] + 0.01f * cntf[t];
    out_count[t] = c;
    red[t]  = c;
    dred[t] = lossb[t];
    __syncthreads();
    for (int s = 512; s >= 1; s >>= 1) {
        if (t < s) { red[t] += red[t + s]; dred[t] += dred[t + s]; }
        __syncthreads();
    }
    float n = red[0];
    cs[t] = (c + 1e-5f) / (n + 1024.0f * 1e-5f) * n;
    if (t == 0) {
        float m = (float)(dred[0] / (double)((size_t)N_Q * D_DIM));
        out_loss[0] = m + 0.25f * m;   // codebook + BETA*commit, bitwise equal halves
    }
}

// ---------------------------------------------------------------------------
// per-code: dw[k,d] = sum over members of z (double accum, 4-way ILP), then
// EMA + normalize. One block per code; thread t handles column d=t.
__global__ void accum_embed_kernel(const float* __restrict__ z,
                                   const int* __restrict__ perm,
                                   const int* __restrict__ icnt,
                                   const int* __restrict__ offs,
                                   const float* __restrict__ cs,
                                   const float* __restrict__ ema_w,
                                   float* __restrict__ out_embed,
                                   float* __restrict__ out_emaw)
{
    __shared__ int rows[256];
    int k = blockIdx.x, t = threadIdx.x;
    int cnt = icnt[k], off = offs[k];
    double a0 = 0.0, a1 = 0.0, a2 = 0.0, a3 = 0.0;
    for (int base = 0; base < cnt; base += 256) {
        int m = min(256, cnt - base);
        __syncthreads();
        if (t < m) rows[t] = perm[off + base + t];
        __syncthreads();
        int r = 0;
        for (; r + 4 <= m; r += 4) {
            a0 += (double)z[(size_t)rows[r+0] * D_DIM + t];
            a1 += (double)z[(size_t)rows[r+1] * D_DIM + t];
            a2 += (double)z[(size_t)rows[r+2] * D_DIM + t];
            a3 += (double)z[(size_t)rows[r+3] * D_DIM + t];
        }
        for (; r < m; ++r) a0 += (double)z[(size_t)rows[r] * D_DIM + t];
    }
    double acc = (a0 + a1) + (a2 + a3);
    float w = 0.99f * ema_w[(size_t)k * D_DIM + t] + 0.01f * (float)acc;
    out_emaw[(size_t)k * D_DIM + t]  = w;
    out_embed[(size_t)k * D_DIM + t] = w / cs[k];
}

// ---------------------------------------------------------------------------
extern "C" void kernel_launch(void* const* d_in, const int* in_sizes, int n_in,
                              void* d_out, int out_size, void* d_ws, size_t ws_size,
                              hipStream_t stream)
{
    const float* z          = (const float*)d_in[0];
    const float* embed      = (const float*)d_in[1];
    const float* ema_count  = (const float*)d_in[2];
    const float* ema_weight = (const float*)d_in[3];
    float* out = (float*)d_out;
    char*  ws  = (char*)d_ws;

    int*      ws_idx  = (int*)(ws + WS_IDX);
    float*    ws_zz   = (float*)(ws + WS_ZZ);
    int*      ws_perm = (int*)(ws + WS_PERM);
    unsigned long long* ws_pack = (unsigned long long*)(ws + WS_PACK);
    float*    ws_en   = (float*)(ws + WS_EN);
    int*      ws_icnt = (int*)(ws + WS_ICNT);
    int*      ws_offs = (int*)(ws + WS_OFFS);
    int*      ws_offw = (int*)(ws + WS_OFFW);
    float*    ws_cntf = (float*)(ws + WS_CNTF);
    float*    ws_cs   = (float*)(ws + WS_CS);
    unsigned* ws_mk   = (unsigned*)(ws + WS_MINKEY);
    float*    ws_thr  = (float*)(ws + WS_THR);
    double*   ws_lb   = (double*)(ws + WS_LOSSB);

    hipMemsetAsync(ws + WS_PACK,   0xFF, (size_t)N_Q * 8, stream);
    hipMemsetAsync(ws + WS_MINKEY, 0xFF, (size_t)N_Q * 4, stream);
    hipMemsetAsync(ws + WS_ICNT,   0, 4096, stream);
    hipMemsetAsync(ws + WS_LOSSB,  0, 8192, stream);

    rownorm2_kernel<<<K_CODES / 4, 256, 0, stream>>>(embed, ws_en);
    rownorm2_kernel<<<N_Q / 4,     256, 0, stream>>>(z, ws_zz);

    sweep_kernel<false><<<N_Q / 128, 256, 0, stream>>>(z, embed, ws_en, ws_zz,
                                                       ws_mk, ws_thr, ws_pack);
    thr_kernel<<<N_Q / 256, 256, 0, stream>>>(ws_mk, ws_thr);
    sweep_kernel<true><<<N_Q / 128, 256, 0, stream>>>(z, embed, ws_en, ws_zz,
                                                      ws_mk, ws_thr, ws_pack);

    unpack_kernel<<<N_Q / 256, 256, 0, stream>>>(ws_pack, ws_idx,
                                                 out + OUT_IDX, ws_icnt);
    scan_kernel<<<1, 1024, 0, stream>>>(ws_icnt, ws_offs, ws_offw, ws_cntf);
    fill_kernel<<<N_Q / 256, 256, 0, stream>>>(ws_idx, ws_offw, ws_perm);
    qst_loss_kernel<<<(N_Q * (D_DIM / 4)) / 256, 256, 0, stream>>>(
        z, embed, ws_idx, out + OUT_QST, ws_lb);
    fin_counts_kernel<<<1, 1024, 0, stream>>>(ema_count, ws_cntf, ws_lb,
                                              out + OUT_COUNT, out + OUT_LOSS, ws_cs);
    accum_embed_kernel<<<K_CODES, 256, 0, stream>>>(z, ws_perm, ws_icnt, ws_offs,
                                                    ws_cs, ema_weight,
                                                    out + OUT_EMBED, out + OUT_EMAW);
}